// Round 9
// baseline (6496.112 us; speedup 1.0000x reference)
//
#include <hip/hip_runtime.h>
#include <hip/hip_bf16.h>

#define VOCAB 78
#define EMBED 8
#define HID 256
#define BATCH 512
#define SEQ 512
#define G4H 1024

#define GB 8    // batch groups
#define GH 32   // hidden groups -> 256 WGs, 1 per CU
#define BS 64   // batch rows per WG
#define HS 8    // hidden cols per WG

typedef short bf16x8 __attribute__((ext_vector_type(8)));
typedef float f32x4 __attribute__((ext_vector_type(4)));
typedef unsigned long long u64;

// ---- workspace layout (bytes) ----
#define OFF_WHH0 0                         // 512KB bf16 [1024][256]
#define OFF_WIH1 (512*1024)
#define OFF_WHH1 (1024*1024)
#define OFF_XG0  (1536*1024)               // 78*1024*4
#define OFF_B1   (OFF_XG0 + 320*1024)
#define OFF_XT   (OFF_B1 + 4096)           // int [512][512]
#define OFF_H0   (OFF_XT + 1024*1024)      // 2 x [512][256] bf16
#define OFF_H1   (OFF_H0 + 512*1024)
#define OFF_H1F  (OFF_H1 + 512*1024)       // [512][256] f32
#define OFF_CNT  (OFF_H1F + 512*1024)      // 32 (gb,wave) pairs x 128B {cnt0, cnt1}
#define WS_NEED  (OFF_CNT + 4096)

__device__ __forceinline__ float sigm(float x){ return 1.f/(1.f + __expf(-x)); }
__device__ __forceinline__ float tanh_f(float x){
  float e = __expf(-2.f * fabsf(x));
  float r = (1.f - e) / (1.f + e);
  return copysignf(r, x);
}
__device__ __forceinline__ unsigned short f2b(float x){
  unsigned u = __float_as_uint(x);
  unsigned r = (u + 0x7FFFu + ((u >> 16) & 1u)) >> 16;
  return (unsigned short)r;
}

// ---------------- prep: bf16 weights, xg0 token table, x transpose, bias1, zero h/counters
__global__ void prep(const int* __restrict__ x, const float* __restrict__ E,
                     const float* __restrict__ Wih0, const float* __restrict__ Whh0,
                     const float* __restrict__ bih0, const float* __restrict__ bhh0,
                     const float* __restrict__ Wih1, const float* __restrict__ Whh1,
                     const float* __restrict__ bih1, const float* __restrict__ bhh1,
                     unsigned char* __restrict__ ws)
{
  unsigned short* Whh0b = (unsigned short*)(ws + OFF_WHH0);
  unsigned short* Wih1b = (unsigned short*)(ws + OFF_WIH1);
  unsigned short* Whh1b = (unsigned short*)(ws + OFF_WHH1);
  float* xg0 = (float*)(ws + OFF_XG0);
  float* b1  = (float*)(ws + OFF_B1);
  int*   xT  = (int*)(ws + OFF_XT);

  long id = (long)blockIdx.x * 256 + threadIdx.x;
  const long NW = 1024L * 256;
  if (id < NW) { Whh0b[id] = f2b(Whh0[id]); return; }
  id -= NW;
  if (id < NW) { Wih1b[id] = f2b(Wih1[id]); return; }
  id -= NW;
  if (id < NW) { Whh1b[id] = f2b(Whh1[id]); return; }
  id -= NW;
  if (id < (long)VOCAB*G4H) {
    int v = (int)(id / G4H), row = (int)(id % G4H);
    float s = bih0[row] + bhh0[row];
    if (v != 0) {
      #pragma unroll
      for (int e = 0; e < EMBED; e++) s += E[v*EMBED + e] * Wih0[row*EMBED + e];
    }
    xg0[id] = s; return;
  }
  id -= (long)VOCAB*G4H;
  if (id < (long)SEQ*BATCH) {
    int t = (int)(id / BATCH), b = (int)(id % BATCH);
    xT[t*BATCH + b] = x[b*SEQ + t]; return;
  }
  id -= (long)SEQ*BATCH;
  if (id < G4H) { b1[id] = bih1[id] + bhh1[id]; return; }
  id -= G4H;
  if (id < 262144) { ((unsigned*)(ws + OFF_H0))[id] = 0u; return; }
  id -= 262144;
  if (id < 1024) { ((unsigned*)(ws + OFF_CNT))[id] = 0u; }
}

// ---------------- weight-stationary LSTM, barrier-free free-running waves
// 256 WGs: gb=bid&7, gh=bid>>3. Wave m of every WG in group gb forms a sync
// subgroup over batch rows [gb*64 + m*16, +16): it reads/writes ONLY those rows.
// Counters per (gb,m): cnt0 (h0 ready) signaled after L0's exchange drains;
// cnt1 (h1 ready) after L1's. Iteration k: spin cnt0>=32k, cnt1>=32(k-1);
// load a0,a1; L0(k)->exch h0->vmcnt0->cnt0+=1; L1(k-1)->exch h1->vmcnt0->cnt1+=1.
// L1 + its signal are OFF the h0 critical path (overlap other WGs' next observe).
__global__ __launch_bounds__(256, 1) void lstm_sync(unsigned char* __restrict__ ws)
{
  const unsigned short* Wg = (const unsigned short*)(ws + OFF_WHH0);
  const float* xg0 = (const float*)(ws + OFF_XG0);
  const float* b1  = (const float*)(ws + OFF_B1);
  const int*   xT  = (const int*)(ws + OFF_XT);
  unsigned short* h0g = (unsigned short*)(ws + OFF_H0);  // [2][512][256]
  unsigned short* h1g = (unsigned short*)(ws + OFF_H1);
  float* h1f = (float*)(ws + OFF_H1F);

  __shared__ __align__(16) unsigned char smem[49152 + 1024];
  unsigned char* wlds = smem;
  unsigned char* hb   = smem + 49152;     // [4 waves][16 rows][8 cols] u16

  const int tid = threadIdx.x;
  const int m = tid >> 6, l = tid & 63, lc = l & 15, lq = l >> 4;
  const int gb = blockIdx.x & 7, gh = blockIdx.x >> 3;
  const int B0 = gb * BS, J = gh * HS;
  const int brow0 = B0 + m*16;

  unsigned* c0p = (unsigned*)(ws + OFF_CNT) + (gb*4 + m)*32;  // 128B/line pair
  unsigned* c1p = c0p + 16;

  // --- stage weight slices into LDS (once), XOR-swizzled. cw = n*16+i.
  for (int idx = tid; idx < 3*2*16*32; idx += 256) {
    int mat = idx >> 10;
    int rem = idx & 1023;
    int cw  = rem >> 5;          // 0..31
    int c16 = rem & 31;          // k-chunk of 8 bf16
    int n = cw >> 4, i = cw & 15;
    int grow = (2*n + (i>>3))*256 + J + (i&7);
    bf16x8 v = *(const bf16x8*)(Wg + (size_t)mat*262144 + (size_t)grow*256 + c16*8);
    *(bf16x8*)(wlds + mat*16384 + cw*512 + ((c16*16) ^ ((i&7)<<4))) = v;
  }

  // bias in MFMA layout: gate 2n+(lc>>3), col J+(lc&7)
  float biasv[2];
  #pragma unroll
  for (int n = 0; n < 2; n++) biasv[n] = b1[(2*n + (lc>>3))*256 + J + (lc&7)];

  int wb[3][2];
  const int swz = (lc & 7) << 4;
  #pragma unroll
  for (int mat = 0; mat < 3; mat++)
    #pragma unroll
    for (int n = 0; n < 2; n++) wb[mat][n] = mat*16384 + (n*16 + lc)*512;
  __syncthreads();   // ONLY barrier: weight staging visible to all waves

  float c0[4] = {0,0,0,0}, c1[4] = {0,0,0,0};
  u64 xret = 0;

#define MM(acc, a, mat)                                                            \
  _Pragma("unroll") for (int kt = 0; kt < 8; kt++) {                               \
    _Pragma("unroll") for (int n = 0; n < 2; n++) {                                \
      bf16x8 bfr = *(const bf16x8*)(wlds + wb[mat][n] + ((kt*64 + lq*16) ^ swz));  \
      acc[n] = __builtin_amdgcn_mfma_f32_16x16x32_bf16(a[kt], bfr, acc[n], 0,0,0); \
    } }

  #pragma unroll 1
  for (int k = 0; k <= SEQ; ++k) {
    const int pk = k & 1, pkm1 = pk ^ 1;

    // ---- per-wave spins (all 64 lanes poll same addr -> 1 coalesced request)
    if (k > 0) {
      unsigned need0 = 32u * (unsigned)k;
      while (__hip_atomic_load(c0p, __ATOMIC_RELAXED, __HIP_MEMORY_SCOPE_AGENT) < need0)
        __builtin_amdgcn_s_sleep(1);
    }
    if (k >= 2) {
      unsigned need1 = 32u * (unsigned)(k - 1);
      while (__hip_atomic_load(c1p, __ATOMIC_RELAXED, __HIP_MEMORY_SCOPE_AGENT) < need1)
        __builtin_amdgcn_s_sleep(1);
    }
    // PIN: h loads below may not hoist above the spins
    asm volatile("" ::: "memory");
    __builtin_amdgcn_sched_barrier(0);

    // ---- coherent h loads (L1/L2-bypassing); frag kt = 64B stride = 8 u64
    bf16x8 a0[8];  // h0(k-1), feeds L0(k) and L1(k-1)
    { const u64* hp = (const u64*)(h0g + (size_t)pkm1*131072 + (size_t)(brow0+lc)*256 + lq*8);
      #pragma unroll
      for (int kt = 0; kt < 8; kt++) {
        union { u64 q[2]; bf16x8 v; } u;
        u.q[0] = __hip_atomic_load(hp + kt*8 + 0, __ATOMIC_RELAXED, __HIP_MEMORY_SCOPE_SYSTEM);
        u.q[1] = __hip_atomic_load(hp + kt*8 + 1, __ATOMIC_RELAXED, __HIP_MEMORY_SCOPE_SYSTEM);
        a0[kt] = u.v;
      } }
    bf16x8 a1[8];  // h1(k-2)
    if (k >= 1) {
      const u64* hp = (const u64*)(h1g + (size_t)pk*131072 + (size_t)(brow0+lc)*256 + lq*8);
      #pragma unroll
      for (int kt = 0; kt < 8; kt++) {
        union { u64 q[2]; bf16x8 v; } u;
        u.q[0] = __hip_atomic_load(hp + kt*8 + 0, __ATOMIC_RELAXED, __HIP_MEMORY_SCOPE_SYSTEM);
        u.q[1] = __hip_atomic_load(hp + kt*8 + 1, __ATOMIC_RELAXED, __HIP_MEMORY_SCOPE_SYSTEM);
        a1[kt] = u.v;
      }
    }

    // ---- L0(k): h0(k) = lstm(h0(k-1), x(k))   [critical path]
    if (k < SEQ) {
      float xg[4][4];
      if (lc < 8) {
        #pragma unroll
        for (int r = 0; r < 4; r++) {
          int tok = xT[k*BATCH + brow0 + lq*4 + r];        // plain: L1/L2-cached
          const float* tr = xg0 + (size_t)tok*G4H + J + lc;
          #pragma unroll
          for (int g = 0; g < 4; g++) xg[g][r] = tr[g*256];
        }
      }
      f32x4 acc0[2] = {{0,0,0,0},{0,0,0,0}};
      MM(acc0, a0, 0);
      float fpre[4], opre[4];
      #pragma unroll
      for (int r = 0; r < 4; r++) {
        fpre[r] = __shfl_xor(acc0[0][r], 8, 64);
        opre[r] = __shfl_xor(acc0[1][r], 8, 64);
      }
      if (lc < 8) {
        #pragma unroll
        for (int r = 0; r < 4; r++) {
          float gi = sigm (acc0[0][r] + xg[0][r]);
          float gf = sigm (fpre[r]    + xg[1][r]);
          float gg = tanh_f(acc0[1][r] + xg[2][r]);
          float go = sigm (opre[r]    + xg[3][r]);
          float c = gf*c0[r] + gi*gg;  c0[r] = c;
          *(unsigned short*)(hb + m*256 + (lq*4 + r)*16 + lc*2) = f2b(go * tanh_f(c));
        }
      }
      // wave-local pack + exchange (32 lanes x u64); lgkmcnt orders hb ds ops
      if (l < 32) {
        int row = l >> 1, half = l & 1;
        u64 pv = *(const u64*)(hb + m*256 + row*16 + half*8);
        u64* dp = (u64*)(h0g + (size_t)pk*131072 + (size_t)(B0 + m*16 + row)*256 + J + half*4);
        xret ^= __hip_atomic_exchange(dp, pv, __ATOMIC_RELAXED, __HIP_MEMORY_SCOPE_AGENT);
      }
      // hand-built release: drain exchange returns, then signal (wave lane 0)
      asm volatile("s_waitcnt vmcnt(0)" ::: "memory");
      __builtin_amdgcn_sched_barrier(0);
      if (l == 0)
        __hip_atomic_fetch_add(c0p, 1u, __ATOMIC_RELAXED, __HIP_MEMORY_SCOPE_AGENT);
    }

    // ---- L1(k-1): h1(k-1) = lstm(h0(k-1), h1(k-2))  [off critical path]
    if (k >= 1) {
      f32x4 acc2[2];
      #pragma unroll
      for (int n = 0; n < 2; n++) { f32x4 v = {biasv[n],biasv[n],biasv[n],biasv[n]}; acc2[n] = v; }
      MM(acc2, a0, 1);
      MM(acc2, a1, 2);
      float fpre[4], opre[4];
      #pragma unroll
      for (int r = 0; r < 4; r++) {
        fpre[r] = __shfl_xor(acc2[0][r], 8, 64);
        opre[r] = __shfl_xor(acc2[1][r], 8, 64);
      }
      if (lc < 8) {
        #pragma unroll
        for (int r = 0; r < 4; r++) {
          float gi = sigm (acc2[0][r]);
          float gf = sigm (fpre[r]);
          float gg = tanh_f(acc2[1][r]);
          float go = sigm (opre[r]);
          float c = gf*c1[r] + gi*gg;  c1[r] = c;
          float h = go * tanh_f(c);
          *(unsigned short*)(hb + m*256 + (lq*4 + r)*16 + lc*2) = f2b(h);
          if (k == SEQ) h1f[(size_t)(brow0 + lq*4 + r)*256 + J + lc] = h;
        }
      }
      if (l < 32) {
        int row = l >> 1, half = l & 1;
        u64 pv = *(const u64*)(hb + m*256 + row*16 + half*8);
        u64* dp = (u64*)(h1g + (size_t)pkm1*131072 + (size_t)(B0 + m*16 + row)*256 + J + half*4);
        xret ^= __hip_atomic_exchange(dp, pv, __ATOMIC_RELAXED, __HIP_MEMORY_SCOPE_AGENT);
      }
      asm volatile("s_waitcnt vmcnt(0)" ::: "memory");
      __builtin_amdgcn_sched_barrier(0);
      if (l == 0)
        __hip_atomic_fetch_add(c1p, 1u, __ATOMIC_RELAXED, __HIP_MEMORY_SCOPE_AGENT);
    }
  }
#undef MM
  asm volatile("" :: "v"(xret));  // keep exchange returns live
}

// ---------------- FC: out[512][78] = h1_last @ Wfc^T + bfc
__global__ void fc_kernel(const unsigned char* __restrict__ ws,
                          const float* __restrict__ Wfc, const float* __restrict__ bfc,
                          float* __restrict__ out)
{
  int b = blockIdx.x, v = threadIdx.x;
  if (v >= VOCAB) return;
  const float* h = (const float*)(ws + OFF_H1F) + (size_t)b*HID;
  const float* w = Wfc + (size_t)v*HID;
  float s = bfc[v];
  #pragma unroll 4
  for (int k = 0; k < HID; k += 4)
    s += h[k]*w[k] + h[k+1]*w[k+1] + h[k+2]*w[k+2] + h[k+3]*w[k+3];
  out[(size_t)b*VOCAB + v] = s;
}

extern "C" void kernel_launch(void* const* d_in, const int* in_sizes, int n_in,
                              void* d_out, int out_size, void* d_ws, size_t ws_size,
                              hipStream_t stream) {
  const int*   x    = (const int*)  d_in[0];
  const float* E    = (const float*)d_in[1];
  const float* Wih0 = (const float*)d_in[2];
  const float* Whh0 = (const float*)d_in[3];
  const float* bih0 = (const float*)d_in[4];
  const float* bhh0 = (const float*)d_in[5];
  const float* Wih1 = (const float*)d_in[6];
  const float* Whh1 = (const float*)d_in[7];
  const float* bih1 = (const float*)d_in[8];
  const float* bhh1 = (const float*)d_in[9];
  const float* Wfc  = (const float*)d_in[10];
  const float* bfc  = (const float*)d_in[11];
  unsigned char* ws = (unsigned char*)d_ws;

  // items: 3*262144 + 79872 + 262144 + 1024 + 262144 + 1024 = 1,392,640 = 5440*256
  prep<<<5440, 256, 0, stream>>>(x, E, Wih0, Whh0, bih0, bhh0, Wih1, Whh1, bih1, bhh1, ws);
  lstm_sync<<<GB*GH, 256, 0, stream>>>(ws);
  fc_kernel<<<BATCH, 128, 0, stream>>>(ws, Wfc, bfc, (float*)d_out);
}